// Round 7
// baseline (975.017 us; speedup 1.0000x reference)
//
#include <hip/hip_runtime.h>
#include <hip/hip_bf16.h>
#include <stdint.h>

#define T_TOK 8192
#define D_DIM 1024
#define E_NUM 8
#define H_DIM 4096
#define PPX 10   // panel slots (256 rows each) per expert; supports ne <= 2560

typedef short bf16x8 __attribute__((ext_vector_type(8)));
typedef float f32x4 __attribute__((ext_vector_type(4)));

#define AS1 __attribute__((address_space(1)))
#define AS3 __attribute__((address_space(3)))

__device__ __forceinline__ unsigned short f2b(float f) {
  union { float f; uint32_t u; } v; v.f = f;
  uint32_t r = (v.u + 0x7fffu + ((v.u >> 16) & 1u)) >> 16;
  return (unsigned short)r;
}

__device__ __forceinline__ float gelu_tanh(float x) {
  float u = 0.7978845608028654f * (x + 0.044715f * x * x * x);
  u = fminf(fmaxf(u, -15.f), 15.f);
  float e = __expf(2.f * u);
  float t = (e - 1.f) / (e + 1.f);
  return 0.5f * x * (1.f + t);
}

__device__ __forceinline__ void gload_lds16(const void* g, void* l) {
  __builtin_amdgcn_global_load_lds((const AS1 uint32_t*)g, (AS3 uint32_t*)l, 16, 0, 0);
}

// ---------------- gate + x->bf16 conversion fused ----------------
__global__ __launch_bounds__(256) void moe_gate_conv(const float* __restrict__ x,
                                                     const float* __restrict__ gw,
                                                     const float* __restrict__ gb,
                                                     unsigned short* __restrict__ xb,
                                                     int2* __restrict__ sel,
                                                     float2* __restrict__ wts,
                                                     int* __restrict__ meta) {
  int lane = threadIdx.x & 63;
  int t = blockIdx.x * 4 + (threadIdx.x >> 6);
  const float* xr = x + (size_t)t * D_DIM;
  unsigned short* xo = xb + (size_t)t * D_DIM;
  float acc[8];
#pragma unroll
  for (int e = 0; e < 8; e++) acc[e] = 0.f;
#pragma unroll
  for (int i = 0; i < 4; i++) {
    int d0 = lane * 4 + i * 256;
    float4 xv = *(const float4*)(xr + d0);
    ushort4 o;
    o.x = f2b(xv.x); o.y = f2b(xv.y); o.z = f2b(xv.z); o.w = f2b(xv.w);
    *(ushort4*)(xo + d0) = o;
    const float* gp = gw + (size_t)d0 * 8;
    float xs[4] = {xv.x, xv.y, xv.z, xv.w};
#pragma unroll
    for (int j = 0; j < 4; j++) {
#pragma unroll
      for (int e = 0; e < 8; e++) acc[e] += xs[j] * gp[j * 8 + e];
    }
  }
#pragma unroll
  for (int off = 32; off > 0; off >>= 1) {
#pragma unroll
    for (int e = 0; e < 8; e++) acc[e] += __shfl_xor(acc[e], off);
  }
  if (lane == 0) {
    float lg[8];
#pragma unroll
    for (int e = 0; e < 8; e++) lg[e] = acc[e] + gb[e];
    int e0 = 0; float b0 = lg[0];
#pragma unroll
    for (int e = 1; e < 8; e++) if (lg[e] > b0) { b0 = lg[e]; e0 = e; }
    int e1 = -1; float b1v = -1e30f;
#pragma unroll
    for (int e = 0; e < 8; e++) if (e != e0 && lg[e] > b1v) { b1v = lg[e]; e1 = e; }
    float d = __expf(b1v - b0);
    float w0 = 1.f / (1.f + d), w1 = d / (1.f + d);
    sel[t] = make_int2(e0, e1);
    wts[t] = make_float2(w0, w1);
    atomicAdd(&meta[e0], 1);
    atomicAdd(&meta[e1], 1);
  }
}

// ---------------- transpose + convert: in [E][R][C] f32 -> out [E][C][R] bf16 ----------------
__global__ __launch_bounds__(256) void moe_transpose(const float* __restrict__ in,
                                                     unsigned short* __restrict__ out,
                                                     int R, int C) {
  int e = blockIdx.z;
  int c0 = blockIdx.x * 64, r0 = blockIdx.y * 64;
  __shared__ float tile[64][65];
  const float* ine = in + (size_t)e * R * C;
  unsigned short* oute = out + (size_t)e * R * C;
  int tr = threadIdx.x >> 2;
  int tc4 = (threadIdx.x & 3) * 16;
#pragma unroll
  for (int p = 0; p < 4; p++) {
    int c = tc4 + p * 4;
    float4 v = *(const float4*)(ine + (size_t)(r0 + tr) * C + c0 + c);
    tile[tr][c] = v.x; tile[tr][c + 1] = v.y; tile[tr][c + 2] = v.z; tile[tr][c + 3] = v.w;
  }
  __syncthreads();
#pragma unroll
  for (int p = 0; p < 4; p++) {
    int rr = tc4 + p * 4;
    ushort4 o;
    o.x = f2b(tile[rr + 0][tr]);
    o.y = f2b(tile[rr + 1][tr]);
    o.z = f2b(tile[rr + 2][tr]);
    o.w = f2b(tile[rr + 3][tr]);
    *(ushort4*)(oute + (size_t)(c0 + tr) * R + r0 + rr) = o;
  }
}

// meta layout: [0..7] counts, [8..16] offsets(+total), [20..27] cursor
__global__ void moe_scan(int* meta) {
  if (threadIdx.x == 0 && blockIdx.x == 0) {
    int o = 0;
    for (int e = 0; e < 8; e++) { meta[8 + e] = o; meta[20 + e] = o; o += meta[e]; }
    meta[16] = o;
  }
}

__global__ __launch_bounds__(256) void moe_scatter(const int2* __restrict__ sel,
                                                   const float2* __restrict__ wts,
                                                   int* __restrict__ meta,
                                                   int* __restrict__ token_id,
                                                   float* __restrict__ weightv) {
  int t = blockIdx.x * 256 + threadIdx.x;
  if (t >= T_TOK) return;
  int2 s = sel[t];
  float2 w = wts[t];
  int p0 = atomicAdd(&meta[20 + s.x], 1); token_id[p0] = t; weightv[p0] = w.x;
  int p1 = atomicAdd(&meta[20 + s.y], 1); token_id[p1] = t; weightv[p1] = w.y;
}

// ---------------- out init: out[t] = w0*b2[e0] + w1*b2[e1] ----------------
__global__ __launch_bounds__(256) void moe_outinit(const int2* __restrict__ sel,
                                                   const float2* __restrict__ wts,
                                                   const float* __restrict__ b2,
                                                   float* __restrict__ out) {
  int t = blockIdx.x;
  int d = threadIdx.x * 4;
  int2 s = sel[t];
  float2 w = wts[t];
  float4 a = *(const float4*)(b2 + (size_t)s.x * D_DIM + d);
  float4 b = *(const float4*)(b2 + (size_t)s.y * D_DIM + d);
  float4 o;
  o.x = w.x * a.x + w.y * b.x;
  o.y = w.x * a.y + w.y * b.y;
  o.z = w.x * a.z + w.y * b.z;
  o.w = w.x * a.w + w.y * b.w;
  *(float4*)(out + (size_t)t * D_DIM + d) = o;
}

// ================= 8-phase-style pipelined grouped GEMM =================
// BM=BN=256, BK=32, 512 thr (8 waves 2Mx4N), 4-buffer LDS ring (128 KiB),
// 2 phases per K-tile, counted vmcnt(8) once per K-tile (tail 4 -> 0),
// stage tile T+3 during tile T, setprio around MFMA clusters.
// MODE 0: h[p] = gelu(x[tok[p]] @ w1[e] + b1[e])
// MODE 1: out[tok[p]] += weight[p] * (h[p] @ w2[e])[ks-half]   (atomic f32)
template<int MODE>
__global__ __launch_bounds__(512, 2) void moe_gemm8p(
    const unsigned short* __restrict__ Amat,
    const unsigned short* __restrict__ Bmat,
    const float* __restrict__ bias,
    const int* __restrict__ meta,
    const int* __restrict__ token_id,
    const float* __restrict__ weightv,
    unsigned short* __restrict__ hout,
    float* __restrict__ yout) {
  constexpr int KLEN = MODE ? 4096 : 1024;
  constexpr int NK   = MODE ? 64 : 32;   // 32-deep K-tiles processed per block

  // decode: expert e = XCD = b&7; within XCD: n fast, (ks,) ps slow
  int b = blockIdx.x;
  int e = b & 7;
  int u = b >> 3;
  int n0, ps, kbase;
  if (MODE) { n0 = (u & 3) * 256; kbase = ((u >> 2) & 1) * 2048; ps = u >> 3; }
  else      { n0 = (u & 15) * 256; kbase = 0; ps = u >> 4; }
  int seg = meta[8 + e], ne = meta[9 + e] - seg;
  int m0 = ps * 256;
  if (m0 >= ne) return;

  __shared__ unsigned short As[4][8192];   // 4 bufs x [256 rows][32 k]
  __shared__ unsigned short Bs[4][8192];

  int tid = threadIdx.x, lane = tid & 63, w = tid >> 6;
  int wm = w >> 2, wn = w & 3;

  // staging: thread covers 16B chunk tid of each 8 KiB half (128 rows x 32 k)
  int srow = tid >> 2;
  int sko  = (tid & 3) * 8;
  const unsigned short* aSrc[2];
  const unsigned short* bSrc[2];
#pragma unroll
  for (int h = 0; h < 2; ++h) {
    int gi = m0 + h * 128 + srow; if (gi >= ne) gi = m0;
    if (MODE) aSrc[h] = Amat + (size_t)(seg + gi) * KLEN + kbase + sko;
    else      aSrc[h] = Amat + (size_t)token_id[seg + gi] * KLEN + sko;
    bSrc[h] = Bmat + (size_t)e * (4096 * 1024)
                   + (size_t)(n0 + h * 128 + srow) * KLEN + kbase + sko;
  }

  auto stageA = [&](int buf, int kt) {
#pragma unroll
    for (int h = 0; h < 2; ++h)
      gload_lds16(aSrc[h] + kt * 32, &As[buf][h * 4096 + w * 512]);
  };
  auto stageB = [&](int buf, int kt) {
#pragma unroll
    for (int h = 0; h < 2; ++h)
      gload_lds16(bSrc[h] + kt * 32, &Bs[buf][h * 4096 + w * 512]);
  };

  f32x4 acc[8][4] = {};
  const int aoff = (wm * 128 + (lane & 15)) * 32 + (lane >> 4) * 8;  // + mf*512
  const int boff = (wn * 64 + (lane & 15)) * 32 + (lane >> 4) * 8;   // + nf*512

  // prologue: tiles 0,1,2 fully staged (12 loads); wait oldest 4 (tile 0)
  stageA(0, 0); stageB(0, 0);
  stageA(1, 1); stageB(1, 1);
  stageA(2, 2); stageB(2, 2);
  asm volatile("s_waitcnt vmcnt(8)" ::: "memory");
  __builtin_amdgcn_s_barrier();

  for (int T = 0; T < NK; ++T) {
    int d = T & 3, s = (T + 3) & 3;
    bool doStage = (T + 3 < NK);

    // ---------- phase A: m-frags 0..3 ----------
    if (doStage) stageA(s, T + 3);
    bf16x8 a0[4], bfr[4];
#pragma unroll
    for (int mf = 0; mf < 4; ++mf) a0[mf] = *(const bf16x8*)&As[d][aoff + mf * 512];
#pragma unroll
    for (int nf = 0; nf < 4; ++nf) bfr[nf] = *(const bf16x8*)&Bs[d][boff + nf * 512];
    __builtin_amdgcn_s_barrier();
    asm volatile("s_waitcnt lgkmcnt(0)" ::: "memory");
    __builtin_amdgcn_sched_barrier(0);
    __builtin_amdgcn_s_setprio(1);
#pragma unroll
    for (int mf = 0; mf < 4; ++mf)
#pragma unroll
      for (int nf = 0; nf < 4; ++nf)
        acc[mf][nf] = __builtin_amdgcn_mfma_f32_16x16x32_bf16(a0[mf], bfr[nf], acc[mf][nf], 0, 0, 0);
    __builtin_amdgcn_s_setprio(0);
    __builtin_amdgcn_s_barrier();

    // ---------- phase B: m-frags 4..7 (reuse B frags) ----------
    if (doStage) stageB(s, T + 3);
    bf16x8 a1[4];
#pragma unroll
    for (int mf = 0; mf < 4; ++mf) a1[mf] = *(const bf16x8*)&As[d][aoff + (mf + 4) * 512];
    __builtin_amdgcn_s_barrier();
    asm volatile("s_waitcnt lgkmcnt(0)" ::: "memory");
    __builtin_amdgcn_sched_barrier(0);
    __builtin_amdgcn_s_setprio(1);
#pragma unroll
    for (int mf = 0; mf < 4; ++mf)
#pragma unroll
      for (int nf = 0; nf < 4; ++nf)
        acc[mf + 4][nf] = __builtin_amdgcn_mfma_f32_16x16x32_bf16(a1[mf], bfr[nf], acc[mf + 4][nf], 0, 0, 0);
    __builtin_amdgcn_s_setprio(0);

    // trailing wait: guarantee tile T+1 landed before anyone reads it
    int rem = NK - 1 - T;
    if (rem >= 3)      { asm volatile("s_waitcnt vmcnt(8)" ::: "memory"); }
    else if (rem == 2) { asm volatile("s_waitcnt vmcnt(4)" ::: "memory"); }
    else if (rem == 1) { asm volatile("s_waitcnt vmcnt(0)" ::: "memory"); }
    __builtin_amdgcn_sched_barrier(0);
    __builtin_amdgcn_s_barrier();
  }

  // ---------------- epilogue ----------------
  int rb = wm * 128 + (lane >> 4) * 4;
  int cb = n0 + wn * 64 + (lane & 15);
  if (MODE) {
#pragma unroll
    for (int mf = 0; mf < 8; ++mf) {
#pragma unroll
      for (int j = 0; j < 4; ++j) {
        int gi = m0 + rb + mf * 16 + j;
        if (gi < ne) {
          int p = seg + gi;
          int tok = token_id[p];
          float wt = weightv[p];
          float* orow = yout + (size_t)tok * D_DIM + cb;
#pragma unroll
          for (int nf = 0; nf < 4; ++nf)
            atomicAdd(&orow[nf * 16], wt * acc[mf][nf][j]);
        }
      }
    }
  } else {
    const float* be = bias + (size_t)e * H_DIM + cb;
    float bvv[4];
#pragma unroll
    for (int nf = 0; nf < 4; ++nf) bvv[nf] = be[nf * 16];
#pragma unroll
    for (int mf = 0; mf < 8; ++mf) {
#pragma unroll
      for (int j = 0; j < 4; ++j) {
        int gi = m0 + rb + mf * 16 + j;
        if (gi < ne) {
          unsigned short* hrow = hout + (size_t)(seg + gi) * H_DIM + cb;
#pragma unroll
          for (int nf = 0; nf < 4; ++nf)
            hrow[nf * 16] = f2b(gelu_tanh(acc[mf][nf][j] + bvv[nf]));
        }
      }
    }
  }
}

extern "C" void kernel_launch(void* const* d_in, const int* in_sizes, int n_in,
                              void* d_out, int out_size, void* d_ws, size_t ws_size,
                              hipStream_t stream) {
  const float* x      = (const float*)d_in[0];
  const float* gate_w = (const float*)d_in[1];
  const float* gate_b = (const float*)d_in[2];
  const float* w1     = (const float*)d_in[3];
  const float* b1     = (const float*)d_in[4];
  const float* w2     = (const float*)d_in[5];
  const float* b2     = (const float*)d_in[6];
  float* out = (float*)d_out;

  uint8_t* ws = (uint8_t*)d_ws;
  unsigned short* hbuf = (unsigned short*)(ws);                 // 128 MiB
  unsigned short* xb   = (unsigned short*)(ws + 134217728ull);  // 16 MiB
  unsigned short* w1t  = (unsigned short*)(ws + 150994944ull);  // 64 MiB
  unsigned short* w2t  = (unsigned short*)(ws + 218103808ull);  // 64 MiB
  int*    token_id = (int*)  (ws + 285212672ull);               // 64 KiB
  float*  weightv  = (float*)(ws + 285278208ull);               // 64 KiB
  float2* wts      = (float2*)(ws + 285343744ull);              // 64 KiB
  int2*   sel      = (int2*) (ws + 285409280ull);               // 64 KiB
  int*    meta     = (int*)  (ws + 285474816ull);               // 512 B

  hipMemsetAsync(meta, 0, 512, stream);

  moe_gate_conv<<<dim3(T_TOK / 4), 256, 0, stream>>>(x, gate_w, gate_b, xb, sel, wts, meta);
  moe_transpose<<<dim3(H_DIM / 64, D_DIM / 64, E_NUM), 256, 0, stream>>>(w1, w1t, D_DIM, H_DIM);
  moe_transpose<<<dim3(D_DIM / 64, H_DIM / 64, E_NUM), 256, 0, stream>>>(w2, w2t, H_DIM, D_DIM);
  moe_scan<<<1, 64, 0, stream>>>(meta);
  moe_scatter<<<dim3(T_TOK / 256), 256, 0, stream>>>(sel, wts, meta, token_id, weightv);
  moe_outinit<<<dim3(T_TOK), 256, 0, stream>>>(sel, wts, b2, out);

  // gemm1: 8 experts(=XCDs) x (16 n-blocks x 10 panel slots)
  moe_gemm8p<0><<<dim3(8 * 16 * PPX), 512, 0, stream>>>(
      xb, w1t, b1, meta, token_id, weightv, hbuf, nullptr);

  // gemm2: 8 experts x (4 n-blocks x 2 k-halves x 10 panel slots)
  moe_gemm8p<1><<<dim3(8 * 4 * 2 * PPX), 512, 0, stream>>>(
      hbuf, w2t, nullptr, meta, token_id, weightv, nullptr, out);
}